// Round 18
// baseline (67.852 us; speedup 1.0000x reference)
//
#include <hip/hip_runtime.h>

#define N_NODES 10000
#define E_EDGES 640000
#define C 128
#define NBA 128           // deg-partial blocks
#define NSTEAL_D 40       // last-arriving k_deg blocks steal dinv fold (40*256 >= 10000)
#define DCH 256           // dinv nodes per stealer
#define NBS 128           // ta partial blocks (same count for tb; 2*NBS scatter blocks)
#define NSTEAL_G 63       // last-arriving k_scatter blocks steal greduce (63*160 >= 10000)
#define CCH 160           // nodes per greduce chunk

typedef float vf4 __attribute__((ext_vector_type(4)));

// Native LDS fp32 add: relaxed, workgroup scope -> ds_add_f32 (no CAS loop).
__device__ __forceinline__ void lds_add(float* p, float v) {
    __hip_atomic_fetch_add(p, v, __ATOMIC_RELAXED, __HIP_MEMORY_SCOPE_WORKGROUP);
}
// NT store: line goes to the memory side, never sits dirty in a producer L2 —
// in-kernel consumers then read clean L3 lines (boundary-quality placement).
__device__ __forceinline__ void nt_store4(float* p, vf4 v) {
    __builtin_nontemporal_store(v, (vf4*)p);
}

// ---------------- k1: deg partials; last 40 arrivers steal the dinv fold ----------
// Block NBA is an aux block computing s1 = colsum(W1) concurrently.
__global__ __launch_bounds__(512) void k_deg(const int* __restrict__ col,
                                             const float* __restrict__ w,
                                             const float* __restrict__ W1,
                                             float* __restrict__ degp,
                                             float* __restrict__ dinv,
                                             float* __restrict__ s1,
                                             unsigned* __restrict__ ctrl) {
    const int tid = threadIdx.x, bid = blockIdx.x;
    if (bid == NBA) {                                     // aux: s1 only
        if (tid < C) {
            float s = 0.0f;
            #pragma unroll 16
            for (int k = 0; k < C; ++k) s += W1[k * C + tid];  // coalesced
            s1[tid] = s;
        }
        return;
    }
    __shared__ float sdeg[N_NODES];                       // 40 KB, 4 blk/CU
    __shared__ int ssteal;
    vf4 z = {0.f, 0.f, 0.f, 0.f};
    for (int i = tid; i < N_NODES / 4; i += 512) ((vf4*)sdeg)[i] = z;
    __syncthreads();
    const int epb = E_EDGES / NBA;                        // 5000
    const int4*   col4 = (const int4*)(col + bid * epb);
    const float4* w4   = (const float4*)(w + bid * epb);
    for (int k = tid; k < epb / 4; k += 512) {
        int4 cc = col4[k]; float4 ww = w4[k];
        lds_add(&sdeg[cc.x], ww.x);
        lds_add(&sdeg[cc.y], ww.y);
        lds_add(&sdeg[cc.z], ww.z);
        lds_add(&sdeg[cc.w], ww.w);
    }
    __syncthreads();
    float* dst = degp + (size_t)bid * N_NODES;
    for (int i = tid; i < N_NODES / 4; i += 512)
        nt_store4(dst + 4 * i, ((const vf4*)sdeg)[i]);    // NT flush -> L3, not L2
    // ---- arrival (release publishes this block's flush) + steal decision ----
    __syncthreads();                                      // flush complete
    if (tid == 0) {
        unsigned old = __hip_atomic_fetch_add(ctrl, 1u, __ATOMIC_ACQ_REL,
                                              __HIP_MEMORY_SCOPE_AGENT);
        ssteal = (int)old - (NBA - NSTEAL_D);             // >=0 for last 40 arrivers
        if (ssteal >= 0 && old < NBA - 1) {               // short tail spin (skew only)
            while (__hip_atomic_load(ctrl, __ATOMIC_ACQUIRE,
                                     __HIP_MEMORY_SCOPE_AGENT) < NBA)
                __builtin_amdgcn_s_sleep(16);
        }
    }
    __syncthreads();
    const int s = ssteal;
    if (s < 0) return;                                    // early arrivers exit, no wait
    // ---- stolen dinv fold: nodes [s*DCH, s*DCH+DCH), NT loads (read-once, L3) ----
    if (tid < DCH) {
        int i = s * DCH + tid;
        if (i < N_NODES) {
            float d = 1.0f;                               // self-loop weight
            #pragma unroll 16
            for (int b = 0; b < NBA; ++b)
                d += __builtin_nontemporal_load(&degp[(size_t)b * N_NODES + i]);
            dinv[i] = rsqrtf(d);
        }
    }
}

// ------ k2: split-half scatter; last 63 arrivers steal greduce; gated final --------
__global__ __launch_bounds__(512) void k_scatter(const int* __restrict__ row,
                                                 const int* __restrict__ col,
                                                 const float* __restrict__ w,
                                                 const float* __restrict__ dinv,
                                                 const float* __restrict__ s1,
                                                 const float* __restrict__ b1,
                                                 const float* __restrict__ W2,
                                                 const float* __restrict__ b2,
                                                 float* __restrict__ tap,
                                                 float* __restrict__ tbp,
                                                 float* __restrict__ g,
                                                 unsigned* __restrict__ ctrl,
                                                 float* __restrict__ out) {
    __shared__ float st[N_NODES];                         // 40 KB, 4 blk/CU
    __shared__ int ssteal, lastFlag;
    const int tid = threadIdx.x;
    const bool isA = blockIdx.x < NBS;
    const int bid  = isA ? blockIdx.x : blockIdx.x - NBS;
    vf4 z = {0.f, 0.f, 0.f, 0.f};
    for (int i = tid; i < N_NODES / 4; i += 512) ((vf4*)st)[i] = z;
    __syncthreads();
    const int epb = E_EDGES / NBS;                        // 5000
    const int4*   row4 = (const int4*)(row + bid * epb);
    const int4*   col4 = (const int4*)(col + bid * epb);
    const float4* w4   = (const float4*)(w + bid * epb);
    if (isA) {                                            // t_a[c] += w * dinv[r]
        for (int k = tid; k < epb / 4; k += 512) {
            int4 rr = row4[k]; int4 cc = col4[k]; float4 ww = w4[k];
            lds_add(&st[cc.x], ww.x * dinv[rr.x]);
            lds_add(&st[cc.y], ww.y * dinv[rr.y]);
            lds_add(&st[cc.z], ww.z * dinv[rr.z]);
            lds_add(&st[cc.w], ww.w * dinv[rr.w]);
        }
    } else {                                              // t_b[r] += w * dinv[c]
        for (int k = tid; k < epb / 4; k += 512) {
            int4 rr = row4[k]; int4 cc = col4[k]; float4 ww = w4[k];
            lds_add(&st[rr.x], ww.x * dinv[cc.x]);
            lds_add(&st[rr.y], ww.y * dinv[cc.y]);
            lds_add(&st[rr.z], ww.z * dinv[cc.z]);
            lds_add(&st[rr.w], ww.w * dinv[cc.w]);
        }
    }
    __syncthreads();
    float* dst = (isA ? tap : tbp) + (size_t)bid * N_NODES;
    for (int i = tid; i < N_NODES / 4; i += 512)
        nt_store4(dst + 4 * i, ((const vf4*)st)[i]);      // NT flush -> L3, not L2
    // ---- arrival + steal decision ----
    __syncthreads();                                      // flush complete
    if (tid == 0) {
        unsigned old = __hip_atomic_fetch_add(ctrl + 32, 1u, __ATOMIC_ACQ_REL,
                                              __HIP_MEMORY_SCOPE_AGENT);
        ssteal = (int)old - (2 * NBS - NSTEAL_G);         // >=0 for last 63 arrivers
        if (ssteal >= 0 && old < 2 * NBS - 1) {           // short tail spin (skew only)
            while (__hip_atomic_load(ctrl + 32, __ATOMIC_ACQUIRE,
                                     __HIP_MEMORY_SCOPE_AGENT) < 2 * NBS)
                __builtin_amdgcn_s_sleep(16);
        }
    }
    __syncthreads();
    const int sidx = ssteal;
    if (sidx < 0) return;                                 // early arrivers exit
    // ---- stolen greduce chunk: nodes [sidx*CCH, ...), NT fold loads (L3) ----
    float* sal = st;                                      // reuse LDS
    float* sbe = st + CCH;
    float* sp  = st + 2 * CCH;
    const int i0 = sidx * CCH;
    int n = N_NODES - i0;
    n = n < 0 ? 0 : (n > CCH ? CCH : n);
    if (tid < n) {                                        // fold t_a -> alpha
        int i = i0 + tid;
        float ta = 0.0f;
        #pragma unroll 16
        for (int b = 0; b < NBS; ++b)
            ta += __builtin_nontemporal_load(&tap[(size_t)b * N_NODES + i]);
        float di = dinv[i];
        sal[tid] = fmaf(di, ta, di * di);
    } else if (tid >= 256 && tid - 256 < n) {             // fold t_b -> beta (parallel)
        int t = tid - 256;
        int i = i0 + t;
        float tb = 0.0f;
        #pragma unroll 16
        for (int b = 0; b < NBS; ++b)
            tb += __builtin_nontemporal_load(&tbp[(size_t)b * N_NODES + i]);
        float di = dinv[i];
        sbe[t] = fmaf(di, tb, di * di);
    }
    __syncthreads();
    const int j   = tid & (C - 1);
    const int sub = tid >> 7;                             // 4 channel-subsets
    float s1j = s1[j], b1j = b1[j], acc = 0.0f;
    for (int t = sub; t < n; t += 4) {                    // LDS broadcast reads
        float h = fmaf(sal[t], s1j, b1j);
        acc += sbe[t] * fmaxf(h, 0.0f);                   // exact relu
    }
    sp[tid] = acc;
    __syncthreads();
    if (tid < C) {
        float G = sp[tid] + sp[tid + 128] + sp[tid + 256] + sp[tid + 384];
        unsafeAtomicAdd(&g[tid], G);                      // native global fadd
    }
    // ---- non-blocking last-block gate for the final matvec (validated R9-R12) ----
    __syncthreads();                                      // g atomics issued
    if (tid == 0) {
        unsigned old = __hip_atomic_fetch_add(ctrl + 64, 1u, __ATOMIC_ACQ_REL,
                                              __HIP_MEMORY_SCOPE_AGENT);
        lastFlag = (old == NSTEAL_G - 1);
        if (lastFlag) __builtin_amdgcn_fence(__ATOMIC_ACQUIRE, "agent");
    }
    __syncthreads();
    if (lastFlag) {
        float a2 = 0.0f;
        #pragma unroll
        for (int k = sub * 32; k < sub * 32 + 32; ++k)
            a2 += g[k] * W2[k * C + j];                   // g broadcast, W2 coalesced
        sp[tid] = a2;
        __syncthreads();
        if (tid < C) {
            float r = sp[tid] + sp[tid + 128] + sp[tid + 256] + sp[tid + 384];
            out[tid] = r * (1.0f / (float)N_NODES) + b2[tid];
        }
    }
}

extern "C" void kernel_launch(void* const* d_in, const int* in_sizes, int n_in,
                              void* d_out, int out_size, void* d_ws, size_t ws_size,
                              hipStream_t stream) {
    const int*   eidx = (const int*)d_in[1];
    const int*   row  = eidx;             // edge_index[0]
    const int*   col  = eidx + E_EDGES;   // edge_index[1]
    const float* w    = (const float*)d_in[2];
    const float* W1   = (const float*)d_in[3];
    const float* b1   = (const float*)d_in[4];
    const float* W2   = (const float*)d_in[5];
    const float* b2   = (const float*)d_in[6];
    float* out = (float*)d_out;
    float* ws  = (float*)d_ws;

    unsigned* ctrl = (unsigned*)ws;                       // 3 counters, 128B apart
    float*    g    = (float*)(ctrl + 96);                 // C
    float*    s1   = g + C;                               // C
    float*    dinv = s1 + C;                              // N
    float*    degp = dinv + N_NODES;                      // NBA * N
    float*    tap  = degp + (size_t)NBA * N_NODES;        // NBS * N
    float*    tbp  = tap  + (size_t)NBS * N_NODES;        // NBS * N

    // zero ctrl + g (896 B) — in-graph, so every replay resets
    (void)hipMemsetAsync(ws, 0, 96 * sizeof(unsigned) + C * sizeof(float), stream);
    k_deg    <<<NBA + 1, 512, 0, stream>>>(col, w, W1, degp, dinv, s1, ctrl);
    k_scatter<<<2 * NBS, 512, 0, stream>>>(row, col, w, dinv, s1, b1, W2, b2,
                                           tap, tbp, g, ctrl, out);
}

// Round 19
// 49.546 us; speedup vs baseline: 1.3695x; 1.3695x over previous
//
#include <hip/hip_runtime.h>

#define N_NODES 10000
#define E_EDGES 640000
#define C 128
#define NBA 128           // deg-partial blocks
#define NBS 128           // ta partial blocks (same count for tb)
#define NBC 63            // greduce blocks (63*160 = 10080 >= 10000)
#define CCH 160           // nodes per greduce block

typedef float vf4 __attribute__((ext_vector_type(4)));

// Native LDS fp32 add: relaxed, workgroup scope -> ds_add_f32 (no CAS loop).
__device__ __forceinline__ void lds_add(float* p, float v) {
    __hip_atomic_fetch_add(p, v, __ATOMIC_RELAXED, __HIP_MEMORY_SCOPE_WORKGROUP);
}

// ---------------- k1: deg partials (LDS scatter by col) ----------------
__global__ __launch_bounds__(512) void k_deg(const int* __restrict__ col,
                                             const float* __restrict__ w,
                                             float* __restrict__ degp) {
    __shared__ float sdeg[N_NODES];                       // 40 KB, 4 blk/CU
    const int tid = threadIdx.x, bid = blockIdx.x;
    vf4 z = {0.f, 0.f, 0.f, 0.f};
    for (int i = tid; i < N_NODES / 4; i += 512) ((vf4*)sdeg)[i] = z;
    __syncthreads();
    const int epb = E_EDGES / NBA;                        // 5000
    const int4*   col4 = (const int4*)(col + bid * epb);
    const float4* w4   = (const float4*)(w + bid * epb);
    for (int k = tid; k < epb / 4; k += 512) {
        int4 cc = col4[k]; float4 ww = w4[k];
        lds_add(&sdeg[cc.x], ww.x);
        lds_add(&sdeg[cc.y], ww.y);
        lds_add(&sdeg[cc.z], ww.z);
        lds_add(&sdeg[cc.w], ww.w);
    }
    __syncthreads();
    float* dst = degp + (size_t)bid * N_NODES;
    for (int i = tid; i < N_NODES / 4; i += 512)
        ((vf4*)dst)[i] = ((const vf4*)sdeg)[i];           // plain coalesced flush
}

// -------- k2: fold deg -> dinv; block 0 also computes s1 and zeroes g/ctrl --------
__global__ __launch_bounds__(256) void k_dinv(const float* __restrict__ degp,
                                              float* __restrict__ dinv,
                                              const float* __restrict__ W1,
                                              float* __restrict__ s1,
                                              float* __restrict__ g,
                                              unsigned* __restrict__ ctrl) {
    int i = blockIdx.x * 256 + threadIdx.x;
    if (i < N_NODES) {
        float d = 1.0f;                                   // self-loop weight
        #pragma unroll 16
        for (int b = 0; b < NBA; ++b) d += degp[(size_t)b * N_NODES + i];
        dinv[i] = rsqrtf(d);
    }
    if (blockIdx.x == 0) {
        if (threadIdx.x < C) {
            int j = threadIdx.x;
            float s = 0.0f;
            #pragma unroll 16
            for (int k = 0; k < C; ++k) s += W1[k * C + j];   // coalesced across j
            s1[j] = s;
            g[j]  = 0.0f;
        }
        if (threadIdx.x == 0) *ctrl = 0u;
    }
}

// ------ k3: split halves. Blocks [0,NBS): t_a (by col); [NBS,2*NBS): t_b (by row) ----
__global__ __launch_bounds__(512) void k_scatter(const int* __restrict__ row,
                                                 const int* __restrict__ col,
                                                 const float* __restrict__ w,
                                                 const float* __restrict__ dinv,
                                                 float* __restrict__ tap,
                                                 float* __restrict__ tbp) {
    __shared__ float st[N_NODES];                         // 40 KB, 4 blk/CU
    const int tid = threadIdx.x;
    const bool isA = blockIdx.x < NBS;
    const int bid  = isA ? blockIdx.x : blockIdx.x - NBS;
    vf4 z = {0.f, 0.f, 0.f, 0.f};
    for (int i = tid; i < N_NODES / 4; i += 512) ((vf4*)st)[i] = z;
    __syncthreads();
    const int epb = E_EDGES / NBS;                        // 5000
    const int4*   row4 = (const int4*)(row + bid * epb);
    const int4*   col4 = (const int4*)(col + bid * epb);
    const float4* w4   = (const float4*)(w + bid * epb);
    if (isA) {                                            // t_a[c] += w * dinv[r]
        for (int k = tid; k < epb / 4; k += 512) {
            int4 rr = row4[k]; int4 cc = col4[k]; float4 ww = w4[k];
            lds_add(&st[cc.x], ww.x * dinv[rr.x]);
            lds_add(&st[cc.y], ww.y * dinv[rr.y]);
            lds_add(&st[cc.z], ww.z * dinv[rr.z]);
            lds_add(&st[cc.w], ww.w * dinv[rr.w]);
        }
    } else {                                              // t_b[r] += w * dinv[c]
        for (int k = tid; k < epb / 4; k += 512) {
            int4 rr = row4[k]; int4 cc = col4[k]; float4 ww = w4[k];
            lds_add(&st[rr.x], ww.x * dinv[cc.x]);
            lds_add(&st[rr.y], ww.y * dinv[cc.y]);
            lds_add(&st[rr.z], ww.z * dinv[cc.z]);
            lds_add(&st[rr.w], ww.w * dinv[cc.w]);
        }
    }
    __syncthreads();
    float* dst = (isA ? tap : tbp) + (size_t)bid * N_NODES;
    for (int i = tid; i < N_NODES / 4; i += 512)
        ((vf4*)dst)[i] = ((const vf4*)st)[i];             // coalesced flush
}

// ---------------- k4: fold -> alpha/beta, channel reduce, g atomics, gated final ----
__global__ __launch_bounds__(512) void k_greduce(const float* __restrict__ tap,
                                                 const float* __restrict__ tbp,
                                                 const float* __restrict__ dinv,
                                                 const float* __restrict__ s1,
                                                 const float* __restrict__ b1,
                                                 const float* __restrict__ W2,
                                                 const float* __restrict__ b2,
                                                 float* __restrict__ g,
                                                 unsigned* __restrict__ ctrl,
                                                 float* __restrict__ out) {
    __shared__ float sal[CCH], sbe[CCH], sp[512];
    __shared__ int lastFlag;
    const int tid = threadIdx.x, bid = blockIdx.x;
    const int i0 = bid * CCH;
    int n = N_NODES - i0;
    n = n < 0 ? 0 : (n > CCH ? CCH : n);
    if (tid < n) {                                        // fold t_a -> alpha
        int i = i0 + tid;
        float ta = 0.0f;
        #pragma unroll 16
        for (int b = 0; b < NBS; ++b) ta += tap[(size_t)b * N_NODES + i];
        float di = dinv[i];
        sal[tid] = fmaf(di, ta, di * di);
    } else if (tid >= 256 && tid - 256 < n) {             // fold t_b -> beta (parallel)
        int t = tid - 256;
        int i = i0 + t;
        float tb = 0.0f;
        #pragma unroll 16
        for (int b = 0; b < NBS; ++b) tb += tbp[(size_t)b * N_NODES + i];
        float di = dinv[i];
        sbe[t] = fmaf(di, tb, di * di);
    }
    __syncthreads();
    const int j   = tid & (C - 1);
    const int sub = tid >> 7;                             // 4 channel-subsets
    float s1j = s1[j], b1j = b1[j], acc = 0.0f;
    for (int t = sub; t < n; t += 4) {                    // LDS broadcast reads
        float h = fmaf(sal[t], s1j, b1j);
        acc += sbe[t] * fmaxf(h, 0.0f);                   // exact relu
    }
    sp[tid] = acc;
    __syncthreads();
    if (tid < C) {
        float G = sp[tid] + sp[tid + 128] + sp[tid + 256] + sp[tid + 384];
        unsafeAtomicAdd(&g[tid], G);                      // native global fadd, 8K total
    }
    // ---- non-blocking last-block gate (validated R9-R18) ----
    __syncthreads();                                      // all g-atomics issued
    if (tid == 0) {
        unsigned old = __hip_atomic_fetch_add(ctrl, 1u, __ATOMIC_ACQ_REL,
                                              __HIP_MEMORY_SCOPE_AGENT);
        lastFlag = (old == NBC - 1);
        if (lastFlag) __builtin_amdgcn_fence(__ATOMIC_ACQUIRE, "agent");
    }
    __syncthreads();
    if (lastFlag) {
        float a2 = 0.0f;
        #pragma unroll
        for (int k = sub * 32; k < sub * 32 + 32; ++k)
            a2 += g[k] * W2[k * C + j];                   // g broadcast, W2 coalesced
        sp[tid] = a2;
        __syncthreads();
        if (tid < C) {
            float r = sp[tid] + sp[tid + 128] + sp[tid + 256] + sp[tid + 384];
            out[tid] = r * (1.0f / (float)N_NODES) + b2[tid];
        }
    }
}

extern "C" void kernel_launch(void* const* d_in, const int* in_sizes, int n_in,
                              void* d_out, int out_size, void* d_ws, size_t ws_size,
                              hipStream_t stream) {
    const int*   eidx = (const int*)d_in[1];
    const int*   row  = eidx;             // edge_index[0]
    const int*   col  = eidx + E_EDGES;   // edge_index[1]
    const float* w    = (const float*)d_in[2];
    const float* W1   = (const float*)d_in[3];
    const float* b1   = (const float*)d_in[4];
    const float* W2   = (const float*)d_in[5];
    const float* b2   = (const float*)d_in[6];
    float* out = (float*)d_out;
    float* ws  = (float*)d_ws;

    float*    degp = ws;                                  // NBA * N
    float*    tap  = degp + (size_t)NBA * N_NODES;        // NBS * N
    float*    tbp  = tap  + (size_t)NBS * N_NODES;        // NBS * N
    float*    dinv = tbp  + (size_t)NBS * N_NODES;        // N
    float*    s1   = dinv + N_NODES;                      // C
    float*    g    = s1 + C;                              // C
    unsigned* ctrl = (unsigned*)(g + C);                  // 1 counter

    k_deg    <<<NBA, 512, 0, stream>>>(col, w, degp);
    k_dinv   <<<(N_NODES + 255) / 256, 256, 0, stream>>>(degp, dinv, W1, s1, g, ctrl);
    k_scatter<<<2 * NBS, 512, 0, stream>>>(row, col, w, dinv, tap, tbp);
    k_greduce<<<NBC, 512, 0, stream>>>(tap, tbp, dinv, s1, b1, W2, b2, g, ctrl, out);
}